// Round 10
// baseline (3614.383 us; speedup 1.0000x reference)
//
#include <hip/hip_runtime.h>
#include <hip/hip_cooperative_groups.h>

namespace cg = cooperative_groups;

// ---- static configuration (mirrors reference) ----
#define N_SHOTS 8
#define NZP 304
#define NXP 304
#define NT 50
#define N_REC 300
#define FLAT (NZP * NXP)          // 92416
#define DT 0.001f
#define INV_DX 0.25f              // 1/4.0
#define INV_DX2 0.0625f           // 1/16.0

#define C23 (2.0f / 3.0f)
#define C112 (1.0f / 12.0f)
#define C43 (4.0f / 3.0f)

// ---------------------------------------------------------------------------
// Shared per-cell step body (identical math to the R7-proven kernel).
// ---------------------------------------------------------------------------
__device__ __forceinline__ void step_cell(
    int shot, int z, int x, int srci, float amp_t,
    const float* __restrict__ v,
    const float* __restrict__ az, const float* __restrict__ bz, const float* __restrict__ dbz,
    const float* __restrict__ ax, const float* __restrict__ bx, const float* __restrict__ dbx,
    const float* __restrict__ wc, float* __restrict__ wp,
    const float* __restrict__ pzi, float* __restrict__ pzo,
    const float* __restrict__ pxi, float* __restrict__ pxo,
    float* __restrict__ zz, float* __restrict__ zx)
{
    const int idx = shot * FLAT + z * NXP + x;
    const float c = wc[idx];

    float xm1 = 0.f, xm2 = 0.f, xp1 = 0.f, xp2 = 0.f;
    float apxm1 = 0.f, apxm2 = 0.f, apxp1 = 0.f, apxp2 = 0.f;
    if (x >= 1)       { xm1 = wc[idx - 1]; apxm1 = ax[x - 1] * pxi[idx - 1]; }
    if (x >= 2)       { xm2 = wc[idx - 2]; apxm2 = ax[x - 2] * pxi[idx - 2]; }
    if (x < NXP - 1)  { xp1 = wc[idx + 1]; apxp1 = ax[x + 1] * pxi[idx + 1]; }
    if (x < NXP - 2)  { xp2 = wc[idx + 2]; apxp2 = ax[x + 2] * pxi[idx + 2]; }

    float zm1 = 0.f, zm2 = 0.f, zp1 = 0.f, zp2 = 0.f;
    float apzm1 = 0.f, apzm2 = 0.f, apzp1 = 0.f, apzp2 = 0.f;
    if (z >= 1)       { zm1 = wc[idx - NXP];     apzm1 = az[z - 1] * pzi[idx - NXP]; }
    if (z >= 2)       { zm2 = wc[idx - 2 * NXP]; apzm2 = az[z - 2] * pzi[idx - 2 * NXP]; }
    if (z < NZP - 1)  { zp1 = wc[idx + NXP];     apzp1 = az[z + 1] * pzi[idx + NXP]; }
    if (z < NZP - 2)  { zp2 = wc[idx + 2 * NXP]; apzp2 = az[z + 2] * pzi[idx + 2 * NXP]; }

    // ---- z-dimension (axis 1) ----
    const float az_ = az[z], bz_ = bz[z], dbz_ = dbz[z];
    const float d1z = ((zp1 - zm1) * C23 + (zm2 - zp2) * C112) * INV_DX;
    const float d2z = (-2.5f * c + C43 * (zp1 + zm1) - C112 * (zp2 + zm2)) * INV_DX2;
    const float dapz = ((apzp1 - apzm1) * C23 + (apzm2 - apzp2) * C112) * INV_DX;
    const float tmpz = (1.f + bz_) * d2z + dbz_ * d1z + dapz;
    const float zz_c = zz[idx];
    const float pz_c = pzi[idx];
    float w_sum = (1.f + bz_) * tmpz + az_ * zz_c;

    // ---- x-dimension (axis 2) ----
    const float ax_ = ax[x], bx_ = bx[x], dbx_ = dbx[x];
    const float d1x = ((xp1 - xm1) * C23 + (xm2 - xp2) * C112) * INV_DX;
    const float d2x = (-2.5f * c + C43 * (xp1 + xm1) - C112 * (xp2 + xm2)) * INV_DX2;
    const float dapx = ((apxp1 - apxm1) * C23 + (apxm2 - apxp2) * C112) * INV_DX;
    const float tmpx = (1.f + bx_) * d2x + dbx_ * d1x + dapx;
    const float zx_c = zx[idx];
    const float px_c = pxi[idx];
    w_sum += (1.f + bx_) * tmpx + ax_ * zx_c;

    // ---- time update ----
    const float vv = v[z * NXP + x];
    float wn = (vv * vv) * (DT * DT) * w_sum + 2.f * c - wp[idx];
    if (z * NXP + x == srci) wn += amp_t;     // source injection (N_SRC == 1)

    wp[idx]  = wn;                            // becomes wc next step
    pzo[idx] = bz_ * d1z + az_ * pz_c;
    pxo[idx] = bx_ * d1x + ax_ * px_c;
    zz[idx]  = bz_ * tmpz + az_ * zz_c;
    zx[idx]  = bx_ * tmpx + ax_ * zx_c;
}

// ---------------------------------------------------------------------------
// Persistent cooperative kernel: ONE launch, NT grid.sync()s.
// 512 blocks x 320 threads = 2 blocks/CU (10 waves/CU; worst-case 3
// waves/SIMD -> launch_bounds(320,3) caps VGPR<=170, wide margin for the
// runtime's co-residency check). shot = bid&7 pins each shot to one XCD.
// Block (s,j), j in [0,64): rows j + 64r (5 rows for j<48, else 4).
// ---------------------------------------------------------------------------
__global__ __launch_bounds__(320, 3) void fdtd_persist(
    const float* __restrict__ v,
    const float* __restrict__ amp,
    const float* __restrict__ az, const float* __restrict__ bz, const float* __restrict__ dbz,
    const float* __restrict__ ax, const float* __restrict__ bx, const float* __restrict__ dbx,
    const int* __restrict__ src_i,
    const int* __restrict__ rec_i,
    float* wf0, float* wf1,
    float* pz0, float* pz1,
    float* px0, float* px1,
    float* zz, float* zx,
    float* rec_out)
{
    cg::grid_group grid = cg::this_grid();
    const int bid = blockIdx.x;
    const int shot = bid & 7;
    const int j = bid >> 3;               // 0..63
    const int tid = threadIdx.x;

    float* wc  = wf0; float* wp  = wf1;
    float* pzi = pz0; float* pzo = pz1;
    float* pxi = px0; float* pxo = px1;

    const int nrows = (j < 48) ? 5 : 4;
    const int srci = src_i[shot];

    for (int t = 0; t < NT; ++t) {
        const float amp_t = amp[t * N_SHOTS + shot];
        if (tid >= NXP) {
            // receiver gather from pre-step wc, same shot only (same XCD)
            int ridx = j * 16 + (tid - NXP);
            if (ridx < N_REC) {
                rec_out[t * (N_SHOTS * N_REC) + shot * N_REC + ridx] =
                    wc[shot * FLAT + rec_i[shot * N_REC + ridx]];
            }
        } else {
            const int x = tid;
            #pragma unroll
            for (int r = 0; r < 5; ++r) {
                if (r < nrows) {
                    step_cell(shot, j + 64 * r, x, srci, amp_t,
                              v, az, bz, dbz, ax, bx, dbx,
                              wc, wp, pzi, pzo, pxi, pxo, zz, zx);
                }
            }
        }

        grid.sync();

        float* tp;
        tp = wc;  wc  = wp;  wp  = tp;
        tp = pzi; pzi = pzo; pzo = tp;
        tp = pxi; pxi = pxo; pxo = tp;
    }
}

// ---------------------------------------------------------------------------
// Fallback: the R7-proven one-kernel-per-step path (453 us).
// ---------------------------------------------------------------------------
__global__ __launch_bounds__(320) void fdtd_step(
    const float* __restrict__ v,
    const float* __restrict__ amp,
    const float* __restrict__ az, const float* __restrict__ bz, const float* __restrict__ dbz,
    const float* __restrict__ ax, const float* __restrict__ bx, const float* __restrict__ dbx,
    const int* __restrict__ src_i,
    const int* __restrict__ rec_i,
    const float* __restrict__ wfc,
    float* __restrict__ wfp,
    const float* __restrict__ pzin, float* __restrict__ pzout,
    const float* __restrict__ pxin, float* __restrict__ pxout,
    float* __restrict__ zzeta, float* __restrict__ xzeta,
    float* __restrict__ rec_out,
    int t)
{
    const int bid = blockIdx.x;
    const int shot = bid & 7;             // XCD pinning (R7-proven)
    const int z = bid >> 3;
    const int tid = threadIdx.x;

    if (tid >= NXP) {
        int gidx = bid * 16 + (tid - NXP);
        if (gidx < N_SHOTS * N_REC) {
            int rshot = gidx / N_REC;
            rec_out[t * (N_SHOTS * N_REC) + gidx] =
                wfc[rshot * FLAT + rec_i[gidx]];
        }
        return;
    }

    step_cell(shot, z, tid, src_i[shot], amp[t * N_SHOTS + shot],
              v, az, bz, dbz, ax, bx, dbx,
              wfc, wfp, pzin, pzout, pxin, pxout, zzeta, xzeta);
}

extern "C" void kernel_launch(void* const* d_in, const int* in_sizes, int n_in,
                              void* d_out, int out_size, void* d_ws, size_t ws_size,
                              hipStream_t stream) {
    const float* v     = (const float*)d_in[0];
    const float* amp   = (const float*)d_in[1];
    const float* az    = (const float*)d_in[2];
    const float* bz    = (const float*)d_in[3];
    const float* dbz   = (const float*)d_in[4];
    const float* ax    = (const float*)d_in[5];
    const float* bx    = (const float*)d_in[6];
    const float* dbx   = (const float*)d_in[7];
    const int* src_i   = (const int*)d_in[8];
    const int* rec_i   = (const int*)d_in[9];
    float* out = (float*)d_out;

    float* ws = (float*)d_ws;
    const size_t A = (size_t)N_SHOTS * FLAT;

    float* wf0 = ws + 0 * A; float* wf1 = ws + 1 * A;
    float* pz0 = ws + 2 * A; float* pz1 = ws + 3 * A;
    float* px0 = ws + 4 * A; float* px1 = ws + 5 * A;
    float* zz  = ws + 6 * A; float* zx  = ws + 7 * A;

    // zero all state (harness re-poisons ws to 0xAA before every call)
    hipMemsetAsync(d_ws, 0, 8 * A * sizeof(float), stream);

    void* args[] = {
        (void*)&v, (void*)&amp,
        (void*)&az, (void*)&bz, (void*)&dbz,
        (void*)&ax, (void*)&bx, (void*)&dbx,
        (void*)&src_i, (void*)&rec_i,
        (void*)&wf0, (void*)&wf1,
        (void*)&pz0, (void*)&pz1,
        (void*)&px0, (void*)&px1,
        (void*)&zz, (void*)&zx,
        (void*)&out
    };
    hipError_t e = hipLaunchCooperativeKernel((const void*)fdtd_persist,
                                              dim3(512), dim3(320), args, 0, stream);
    if (e != hipSuccess) {
        // Fallback: proven 50-launch path (same math; deterministic choice,
        // so graph capture records a consistent node set).
        float* wf[2] = { wf0, wf1 };
        float* pz[2] = { pz0, pz1 };
        float* px[2] = { px0, px1 };
        int cur = 0;
        for (int t = 0; t < NT; ++t) {
            fdtd_step<<<N_SHOTS * NZP, 320, 0, stream>>>(
                v, amp, az, bz, dbz, ax, bx, dbx, src_i, rec_i,
                wf[cur], wf[1 - cur],
                pz[cur], pz[1 - cur],
                px[cur], px[1 - cur],
                zz, zx, out, t);
            cur ^= 1;
        }
    }
}

// Round 11
// 434.115 us; speedup vs baseline: 8.3259x; 8.3259x over previous
//
#include <hip/hip_runtime.h>

// ---- static configuration (mirrors reference) ----
#define N_SHOTS 8
#define NZP 304
#define NXP 304
#define NT 50
#define N_REC 300
#define FLAT (NZP * NXP)          // 92416
#define DT 0.001f
#define INV_DX 0.25f              // 1/4.0
#define INV_DX2 0.0625f           // 1/16.0

#define C23 (2.0f / 3.0f)
#define C112 (1.0f / 12.0f)
#define C43 (4.0f / 3.0f)

union F4 { float4 v; float f[4]; };

__device__ __forceinline__ F4 ldf4(const float* p) {
    F4 r; r.v = *reinterpret_cast<const float4*>(p); return r;
}
__device__ __forceinline__ F4 zf4() {
    F4 r; r.v = make_float4(0.f, 0.f, 0.f, 0.f); return r;
}

// One FDTD step, float4-vectorized along x.
// Grid = 608 blocks (8 shots x 76 row-groups), 320 threads:
//   tid<304: r=tid/76 (row in group), i=tid%76 (x-chunk of 4 cells)
//   tid>=304 & jg<19: receiver gather (same shot -> same XCD)
// shot = bid&7 pins each shot to one XCD (R7-proven, -23%).
// VMEM per 4 cells: ~24 float4 + 7 scalar loads + 5 float4 stores
// (vs ~124 scalar VMEM in the R7 scalar kernel).
__global__ __launch_bounds__(320) void fdtd_step4(
    const float* __restrict__ v,
    const float* __restrict__ amp,        // (NT, N_SHOTS, 1)
    const float* __restrict__ az, const float* __restrict__ bz, const float* __restrict__ dbz,
    const float* __restrict__ ax, const float* __restrict__ bx, const float* __restrict__ dbx,
    const int* __restrict__ src_i,
    const int* __restrict__ rec_i,
    const float* __restrict__ wc,         // current wavefield (read-only)
    float* __restrict__ wp,               // prev wavefield; overwritten with new
    const float* __restrict__ pzi, float* __restrict__ pzo,
    const float* __restrict__ pxi, float* __restrict__ pxo,
    float* __restrict__ zz, float* __restrict__ zx,
    float* __restrict__ rec_out,          // (NT, N_SHOTS, N_REC)
    int t)
{
    const int bid = blockIdx.x;
    const int shot = bid & 7;
    const int jg = bid >> 3;              // 0..75
    const int tid = threadIdx.x;

    if (tid >= 304) {
        if (jg < 19) {
            int ridx = jg * 16 + (tid - 304);
            if (ridx < N_REC) {
                rec_out[t * (N_SHOTS * N_REC) + shot * N_REC + ridx] =
                    wc[shot * FLAT + rec_i[shot * N_REC + ridx]];
            }
        }
        return;
    }

    const int r = tid / 76;
    const int i = tid - r * 76;           // x-chunk index, 0..75
    const int z = jg * 4 + r;
    const int x0 = 4 * i;
    const int idx = shot * FLAT + z * NXP + x0;

    // ---- x-direction: 12-wide windows of wfc and (ax*pxi) ----
    const bool lok = (i > 0), rok = (i < 75);
    F4 wCx = ldf4(wc + idx);
    F4 wLx = lok ? ldf4(wc + idx - 4) : zf4();
    F4 wRx = rok ? ldf4(wc + idx + 4) : zf4();
    F4 pCx = ldf4(pxi + idx);
    F4 pLx = lok ? ldf4(pxi + idx - 4) : zf4();
    F4 pRx = rok ? ldf4(pxi + idx + 4) : zf4();
    F4 aCx = ldf4(ax + x0);
    F4 aLx = lok ? ldf4(ax + x0 - 4) : zf4();
    F4 aRx = rok ? ldf4(ax + x0 + 4) : zf4();

    float wx[12], apx[12];
    #pragma unroll
    for (int k = 0; k < 4; ++k) {
        wx[k]     = wLx.f[k];  apx[k]     = aLx.f[k] * pLx.f[k];
        wx[4 + k] = wCx.f[k];  apx[4 + k] = aCx.f[k] * pCx.f[k];
        wx[8 + k] = wRx.f[k];  apx[8 + k] = aRx.f[k] * pRx.f[k];
    }

    // ---- z-direction: neighbor rows ----
    const bool m1 = (z >= 1), m2 = (z >= 2), p1 = (z < NZP - 1), p2 = (z < NZP - 2);
    F4 wzm1 = m1 ? ldf4(wc + idx - NXP)     : zf4();
    F4 wzm2 = m2 ? ldf4(wc + idx - 2 * NXP) : zf4();
    F4 wzp1 = p1 ? ldf4(wc + idx + NXP)     : zf4();
    F4 wzp2 = p2 ? ldf4(wc + idx + 2 * NXP) : zf4();
    const float azm1 = m1 ? az[z - 1] : 0.f;
    const float azm2 = m2 ? az[z - 2] : 0.f;
    const float azp1 = p1 ? az[z + 1] : 0.f;
    const float azp2 = p2 ? az[z + 2] : 0.f;
    F4 qzm1 = m1 ? ldf4(pzi + idx - NXP)     : zf4();
    F4 qzm2 = m2 ? ldf4(pzi + idx - 2 * NXP) : zf4();
    F4 qzp1 = p1 ? ldf4(pzi + idx + NXP)     : zf4();
    F4 qzp2 = p2 ? ldf4(pzi + idx + 2 * NXP) : zf4();
    #pragma unroll
    for (int k = 0; k < 4; ++k) {
        qzm1.f[k] *= azm1; qzm2.f[k] *= azm2;
        qzp1.f[k] *= azp1; qzp2.f[k] *= azp2;
    }

    // ---- center-cell state ----
    F4 pzC = ldf4(pzi + idx);
    F4 zzC = ldf4(zz + idx);
    F4 zxC = ldf4(zx + idx);
    F4 vC  = ldf4(v + z * NXP + x0);
    F4 wpC = ldf4(wp + idx);
    F4 bxC = ldf4(bx + x0);
    F4 dxC = ldf4(dbx + x0);
    const float azc = az[z], bzc = bz[z], dbzc = dbz[z];
    const int srci = src_i[shot];
    const float amp_t = amp[t * N_SHOTS + shot];

    F4 o_w, o_pz, o_px, o_zz, o_zx;

    #pragma unroll
    for (int k = 0; k < 4; ++k) {
        const float c = wx[4 + k];
        // x-derivatives from the 12-wide windows
        const float d1x  = ((wx[5 + k] - wx[3 + k]) * C23 + (wx[2 + k] - wx[6 + k]) * C112) * INV_DX;
        const float d2x  = (-2.5f * c + C43 * (wx[5 + k] + wx[3 + k]) - C112 * (wx[6 + k] + wx[2 + k])) * INV_DX2;
        const float dapx = ((apx[5 + k] - apx[3 + k]) * C23 + (apx[2 + k] - apx[6 + k]) * C112) * INV_DX;
        // z-derivatives
        const float d1z  = ((wzp1.f[k] - wzm1.f[k]) * C23 + (wzm2.f[k] - wzp2.f[k]) * C112) * INV_DX;
        const float d2z  = (-2.5f * c + C43 * (wzp1.f[k] + wzm1.f[k]) - C112 * (wzp2.f[k] + wzm2.f[k])) * INV_DX2;
        const float dapz = ((qzp1.f[k] - qzm1.f[k]) * C23 + (qzm2.f[k] - qzp2.f[k]) * C112) * INV_DX;

        const float tmpz = (1.f + bzc) * d2z + dbzc * d1z + dapz;
        float w_sum = (1.f + bzc) * tmpz + azc * zzC.f[k];

        const float bxk = bxC.f[k], axk = aCx.f[k];
        const float tmpx = (1.f + bxk) * d2x + dxC.f[k] * d1x + dapx;
        w_sum += (1.f + bxk) * tmpx + axk * zxC.f[k];

        const float vv = vC.f[k];
        float wn = (vv * vv) * (DT * DT) * w_sum + 2.f * c - wpC.f[k];
        if (z * NXP + x0 + k == srci) wn += amp_t;

        o_w.f[k]  = wn;
        o_pz.f[k] = bzc * d1z + azc * pzC.f[k];
        o_px.f[k] = bxk * d1x + apx[4 + k];         // a[x]*px center reused
        o_zz.f[k] = bzc * tmpz + azc * zzC.f[k];
        o_zx.f[k] = bxk * tmpx + axk * zxC.f[k];
    }

    *reinterpret_cast<float4*>(wp + idx)  = o_w.v;
    *reinterpret_cast<float4*>(pzo + idx) = o_pz.v;
    *reinterpret_cast<float4*>(pxo + idx) = o_px.v;
    *reinterpret_cast<float4*>(zz + idx)  = o_zz.v;
    *reinterpret_cast<float4*>(zx + idx)  = o_zx.v;
}

extern "C" void kernel_launch(void* const* d_in, const int* in_sizes, int n_in,
                              void* d_out, int out_size, void* d_ws, size_t ws_size,
                              hipStream_t stream) {
    const float* v     = (const float*)d_in[0];
    const float* amp   = (const float*)d_in[1];
    const float* az    = (const float*)d_in[2];
    const float* bz    = (const float*)d_in[3];
    const float* dbz   = (const float*)d_in[4];
    const float* ax    = (const float*)d_in[5];
    const float* bx    = (const float*)d_in[6];
    const float* dbx   = (const float*)d_in[7];
    const int* src_i   = (const int*)d_in[8];
    const int* rec_i   = (const int*)d_in[9];
    float* out = (float*)d_out;

    float* ws = (float*)d_ws;
    const size_t A = (size_t)N_SHOTS * FLAT;

    // Layout: [wf0, wf1, pz0, px0, zz, zx | pz1, px1] — first 6 need zeroing;
    // pz1/px1 are fully written at t=0 before being read.
    float* wf0 = ws + 0 * A; float* wf1 = ws + 1 * A;
    float* pz0 = ws + 2 * A; float* px0 = ws + 3 * A;
    float* zz  = ws + 4 * A; float* zx  = ws + 5 * A;
    float* pz1 = ws + 6 * A; float* px1 = ws + 7 * A;

    hipMemsetAsync(d_ws, 0, 6 * A * sizeof(float), stream);

    float* wf[2] = { wf0, wf1 };
    float* pz[2] = { pz0, pz1 };
    float* px[2] = { px0, px1 };

    int cur = 0;
    for (int t = 0; t < NT; ++t) {
        fdtd_step4<<<8 * 76, 320, 0, stream>>>(
            v, amp, az, bz, dbz, ax, bx, dbx, src_i, rec_i,
            wf[cur], wf[1 - cur],
            pz[cur], pz[1 - cur],
            px[cur], px[1 - cur],
            zz, zx, out, t);
        cur ^= 1;
    }
}